// Round 2
// baseline (767.336 us; speedup 1.0000x reference)
//
#include <hip/hip_runtime.h>
#include <stdint.h>

#define B_N 2048
#define Z_N 128
#define A_N 4
#define D_N 50000
#define EPS_F 1e-8f

typedef __attribute__((ext_vector_type(8))) short short8;
typedef __attribute__((ext_vector_type(4))) float f32x4;

__device__ __forceinline__ unsigned short f2bf(float f) {
  unsigned int u = __builtin_bit_cast(unsigned int, f);
  u += 0x7FFFu + ((u >> 16) & 1u);   // RNE
  return (unsigned short)(u >> 16);
}

// ------------------------------------------------------------------
// P1: normalize batch_x rows, route samples into per-action lists
// ------------------------------------------------------------------
__global__ void k_qnorm_route(const float* __restrict__ x, const int* __restrict__ act,
                              float* __restrict__ qn, int* __restrict__ counts,
                              int* __restrict__ lists) {
  int w = threadIdx.x >> 6, lane = threadIdx.x & 63;
  int row = blockIdx.x * 4 + w;                 // < 2048
  const float2 v = ((const float2*)(x + (size_t)row * Z_N))[lane];
  float ss = v.x * v.x + v.y * v.y;
#pragma unroll
  for (int m = 1; m < 64; m <<= 1) ss += __shfl_xor(ss, m);
  float inv = 1.0f / (sqrtf(ss) + EPS_F);
  float2 o; o.x = v.x * inv; o.y = v.y * inv;
  ((float2*)(qn + (size_t)row * Z_N))[lane] = o;
  if (lane == 0) {
    int a = act[row];
    int pos = atomicAdd(&counts[a], 1);
    lists[a * B_N + pos] = row;
  }
}

// ------------------------------------------------------------------
// P2: normalize keys rows -> bf16 Kn[a][d][z]
// ------------------------------------------------------------------
__global__ void k_keynorm(const float* __restrict__ keys, unsigned short* __restrict__ kn) {
  int w = threadIdx.x >> 6, lane = threadIdx.x & 63;
  size_t row = (size_t)blockIdx.x * 4 + w;      // < A*D = 200000
  const float2 v = ((const float2*)(keys + row * Z_N))[lane];
  float ss = v.x * v.x + v.y * v.y;
#pragma unroll
  for (int m = 1; m < 64; m <<= 1) ss += __shfl_xor(ss, m);
  float inv = 1.0f / (sqrtf(ss) + EPS_F);
  unsigned int packed = ((unsigned int)f2bf(v.y * inv) << 16) | f2bf(v.x * inv);
  ((unsigned int*)(kn + row * Z_N))[lane] = packed;
}

// ------------------------------------------------------------------
// P3: transpose vals -> bf16 Vt[a][z][d]
// ------------------------------------------------------------------
__global__ void k_vtrans(const float* __restrict__ vals, unsigned short* __restrict__ vt) {
  __shared__ float tile[64][65];
  int a = blockIdx.z, d0 = blockIdx.x * 64, z0 = blockIdx.y * 64;
  int t = threadIdx.x;
  int r = t >> 4, c4 = (t & 15) * 4;
#pragma unroll
  for (int i = 0; i < 4; ++i) {
    int dr = r + i * 16, d = d0 + dr;
    if (d < D_N) {
      const float4 v = *(const float4*)(vals + ((size_t)a * D_N + d) * Z_N + z0 + c4);
      tile[dr][c4 + 0] = v.x; tile[dr][c4 + 1] = v.y;
      tile[dr][c4 + 2] = v.z; tile[dr][c4 + 3] = v.w;
    }
  }
  __syncthreads();
  int zz = t >> 2, dg = (t & 3) * 16;
  if (d0 + dg < D_N) {
    union { unsigned short u[16]; uint4 q[2]; } pk;
#pragma unroll
    for (int j = 0; j < 16; ++j) pk.u[j] = f2bf(tile[dg + j][zz]);
    unsigned short* dst = vt + ((size_t)a * Z_N + z0 + zz) * D_N + d0 + dg;
    ((uint4*)dst)[0] = pk.q[0];
    ((uint4*)dst)[1] = pk.q[1];
  }
}

// ------------------------------------------------------------------
// F: routed flash attention, bf16 MFMA 16x16x32, chunked over D.
//    63 chunks x ~4 tiles x 4 actions -> ~1080 active blocks (~4.2/CU).
//    Register double-buffer: tile k+1 global loads issue right after the
//    second barrier and overlap all of tile k's compute.
// ------------------------------------------------------------------
#define TILE_B 128
#define KT 32
#define CHUNK 800    // 25*32 ; 63 chunks cover 50400 >= D
#define NITER 25
#define NCHUNK 63

__launch_bounds__(256, 4)
__global__ void k_flash(const unsigned short* __restrict__ kn,
                        const unsigned short* __restrict__ vt,
                        const float* __restrict__ qn,
                        const int* __restrict__ counts,
                        const int* __restrict__ lists,
                        float* __restrict__ acc,
                        float* __restrict__ sume) {
  int a = blockIdx.z, ty = blockIdx.y;
  int nb = counts[a];
  if (ty * TILE_B >= nb) return;

  __shared__ unsigned short Kl[KT * 136];       // [key][z], pad 136
  __shared__ unsigned short Vl[128 * 40];       // [z][key], pad 40
  __shared__ unsigned short Pl[4][32 * 40];     // per-wave P tile [sample][key], pad 40

  int t = threadIdx.x;
  int w = t >> 6, lane = t & 63;
  int lq = lane >> 4, ln = lane & 15;

  const unsigned short* kn_a = kn + (size_t)a * D_N * Z_N;
  const unsigned short* vt_a = vt + (size_t)a * Z_N * D_N;
  const int* list_a = lists + a * B_N;

  // Q fragments: A-layout, lane holds Q[sample=ln][z = c*32 + lq*8 + j]
  short8 qf[2][4];
#pragma unroll
  for (int mt = 0; mt < 2; ++mt) {
    int g = ty * TILE_B + w * 32 + mt * 16 + ln;
    bool valid = g < nb;
    int si = valid ? list_a[g] : 0;
#pragma unroll
    for (int c = 0; c < 4; ++c) {
      float4 f0 = {0.f, 0.f, 0.f, 0.f}, f1 = {0.f, 0.f, 0.f, 0.f};
      if (valid) {
        const float* qp = qn + (size_t)si * Z_N + c * 32 + lq * 8;
        f0 = *(const float4*)qp;
        f1 = *(const float4*)(qp + 4);
      }
      short8 s;
      s[0] = (short)f2bf(f0.x); s[1] = (short)f2bf(f0.y);
      s[2] = (short)f2bf(f0.z); s[3] = (short)f2bf(f0.w);
      s[4] = (short)f2bf(f1.x); s[5] = (short)f2bf(f1.y);
      s[6] = (short)f2bf(f1.z); s[7] = (short)f2bf(f1.w);
      qf[mt][c] = s;
    }
  }

  f32x4 O[2][8];
#pragma unroll
  for (int mt = 0; mt < 2; ++mt)
#pragma unroll
    for (int zt = 0; zt < 8; ++zt) O[mt][zt] = (f32x4){0.f, 0.f, 0.f, 0.f};
  float rs[2][4] = {{0.f, 0.f, 0.f, 0.f}, {0.f, 0.f, 0.f, 0.f}};

  int d_base = blockIdx.x * CHUNK;
  int sk_key = t >> 3, sk_z = (t & 7) * 16;     // K staging: 32B per thread
  int sv_z = t >> 1, sv_k = (t & 1) * 16;       // V staging: 32B per thread

  const uint4 z4 = {0u, 0u, 0u, 0u};
  uint4 kA, kB, vA, vB;

  // prefetch tile 0
  {
    int key = d_base + sk_key;
    bool kok = key < D_N;
    const uint4* ksrc = (const uint4*)(kn_a + (size_t)key * Z_N + sk_z);
    kA = kok ? ksrc[0] : z4;
    kB = kok ? ksrc[1] : z4;
    int kk = d_base + sv_k;
    const unsigned short* vsrc = vt_a + (size_t)sv_z * D_N + kk;
    vA = (kk < D_N)     ? *(const uint4*)vsrc       : z4;
    vB = (kk + 8 < D_N) ? *(const uint4*)(vsrc + 8) : z4;
  }

  for (int kt = 0; kt < NITER; ++kt) {
    int d0 = d_base + kt * KT;
    __syncthreads();                            // prev iter's LDS reads done
    {   // commit prefetched tile to LDS
      uint4* kd = (uint4*)&Kl[sk_key * 136 + sk_z];
      kd[0] = kA; kd[1] = kB;
      uint4* vd = (uint4*)&Vl[sv_z * 40 + sv_k];
      vd[0] = vA; vd[1] = vB;
    }
    __syncthreads();
    if (kt + 1 < NITER) {                       // issue next tile's loads NOW
      int d1 = d0 + KT;
      int key = d1 + sk_key;
      bool kok = key < D_N;
      const uint4* ksrc = (const uint4*)(kn_a + (size_t)key * Z_N + sk_z);
      kA = kok ? ksrc[0] : z4;
      kB = kok ? ksrc[1] : z4;
      int kk = d1 + sv_k;
      const unsigned short* vsrc = vt_a + (size_t)sv_z * D_N + kk;
      vA = (kk < D_N)     ? *(const uint4*)vsrc       : z4;
      vB = (kk + 8 < D_N) ? *(const uint4*)(vsrc + 8) : z4;
    }

    // S = Qn . Kn^T   (M=16 samples, N=16 keys, K=Z accumulated over 4 chunks)
    f32x4 S[2][2];
#pragma unroll
    for (int nt = 0; nt < 2; ++nt) {
      short8 kf[4];
#pragma unroll
      for (int c = 0; c < 4; ++c)
        kf[c] = *(const short8*)&Kl[(nt * 16 + ln) * 136 + c * 32 + lq * 8];
#pragma unroll
      for (int mt = 0; mt < 2; ++mt) {
        f32x4 s4 = (f32x4){0.f, 0.f, 0.f, 0.f};
#pragma unroll
        for (int c = 0; c < 4; ++c)
          s4 = __builtin_amdgcn_mfma_f32_16x16x32_bf16(qf[mt][c], kf[c], s4, 0, 0, 0);
        S[mt][nt] = s4;
      }
    }

    // exp (no max-sub needed: |sim|<=~1), rowsum partials, P -> LDS (C->A layout)
#pragma unroll
    for (int mt = 0; mt < 2; ++mt)
#pragma unroll
      for (int nt = 0; nt < 2; ++nt) {
        bool kv = (d0 + nt * 16 + ln) < D_N;
#pragma unroll
        for (int r = 0; r < 4; ++r) {
          float e = kv ? __expf(S[mt][nt][r]) : 0.f;
          rs[mt][r] += e;
          Pl[w][(mt * 16 + lq * 4 + r) * 40 + nt * 16 + ln] = f2bf(e);
        }
      }

    // O += P . V
    short8 pf0 = *(const short8*)&Pl[w][(ln) * 40 + lq * 8];
    short8 pf1 = *(const short8*)&Pl[w][(16 + ln) * 40 + lq * 8];
#pragma unroll
    for (int zt = 0; zt < 8; ++zt) {
      short8 vf = *(const short8*)&Vl[(zt * 16 + ln) * 40 + lq * 8];
      O[0][zt] = __builtin_amdgcn_mfma_f32_16x16x32_bf16(pf0, vf, O[0][zt], 0, 0, 0);
      O[1][zt] = __builtin_amdgcn_mfma_f32_16x16x32_bf16(pf1, vf, O[1][zt], 0, 0, 0);
    }
  }

  // full rowsums: reduce over the 16 lanes of each quad-group
#pragma unroll
  for (int mt = 0; mt < 2; ++mt)
#pragma unroll
    for (int r = 0; r < 4; ++r) {
      float v = rs[mt][r];
      v += __shfl_xor(v, 1); v += __shfl_xor(v, 2);
      v += __shfl_xor(v, 4); v += __shfl_xor(v, 8);
      rs[mt][r] = v;
    }

  // scatter partials: C-layout rows = lq*4+r, col z = ln
#pragma unroll
  for (int mt = 0; mt < 2; ++mt)
#pragma unroll
    for (int r = 0; r < 4; ++r) {
      int g = ty * TILE_B + w * 32 + mt * 16 + lq * 4 + r;
      if (g < nb) {
        int si = list_a[g];
        float* arow = acc + (size_t)si * Z_N + ln;
#pragma unroll
        for (int zt = 0; zt < 8; ++zt) atomicAdd(arow + zt * 16, O[mt][zt][r]);
        if (ln == 0) atomicAdd(&sume[si], rs[mt][r]);
      }
    }
}

// ------------------------------------------------------------------
// F2: pred = acc/sume, accumulate sum of squared error (1 atomic/block)
// ------------------------------------------------------------------
__global__ void k_loss(const float* __restrict__ acc, const float* __restrict__ sume,
                       const float* __restrict__ nxt, float* __restrict__ loss) {
  __shared__ float ls[4];
  int w = threadIdx.x >> 6, lane = threadIdx.x & 63;
  int row = blockIdx.x * 4 + w;
  float inv = 1.0f / sume[row];
  const float2 p2 = ((const float2*)(acc + (size_t)row * Z_N))[lane];
  const float2 n2 = ((const float2*)(nxt + (size_t)row * Z_N))[lane];
  float dx = p2.x * inv - n2.x, dy = p2.y * inv - n2.y;
  float s = dx * dx + dy * dy;
#pragma unroll
  for (int m = 1; m < 64; m <<= 1) s += __shfl_xor(s, m);
  if (lane == 0) ls[w] = s;
  __syncthreads();
  if (threadIdx.x == 0) atomicAdd(loss, ls[0] + ls[1] + ls[2] + ls[3]);
}

__global__ void k_final(const float* __restrict__ loss, float* __restrict__ out) {
  out[0] = loss[0] * (1.0f / (float)(B_N * Z_N));
}

// ------------------------------------------------------------------
// ws layout (bytes):
//  qn      @ 0          1,048,576
//  acc     @ 1,048,576  1,048,576   (zeroed)
//  sume    @ 2,097,152      8,192   (zeroed)
//  counts  @ 2,105,344         16   (zeroed)
//  loss    @ 2,105,360         16   (zeroed)
//  lists   @ 2,105,376     32,768
//  Kn bf16 @ 2,138,368 51,200,000
//  Vt bf16 @ 53,338,368 51,200,000   -> total ~104.5 MB
// ------------------------------------------------------------------
extern "C" void kernel_launch(void* const* d_in, const int* in_sizes, int n_in,
                              void* d_out, int out_size, void* d_ws, size_t ws_size,
                              hipStream_t stream) {
  const float* x    = (const float*)d_in[0];
  const float* nxt  = (const float*)d_in[1];
  const float* keys = (const float*)d_in[2];
  const float* vals = (const float*)d_in[3];
  const int*   act  = (const int*)d_in[4];

  char* ws = (char*)d_ws;
  float* qn     = (float*)(ws + 0);
  float* acc    = (float*)(ws + 1048576);
  float* sume   = (float*)(ws + 2097152);
  int*   counts = (int*)(ws + 2105344);
  float* loss   = (float*)(ws + 2105360);
  int*   lists  = (int*)(ws + 2105376);
  unsigned short* kn = (unsigned short*)(ws + 2138368);
  unsigned short* vt = (unsigned short*)(ws + 53338368);

  hipMemsetAsync(ws + 1048576, 0, 1056800, stream);

  k_qnorm_route<<<512, 256, 0, stream>>>(x, act, qn, counts, lists);
  k_keynorm<<<50000, 256, 0, stream>>>(keys, kn);
  k_vtrans<<<dim3(782, 2, A_N), 256, 0, stream>>>(vals, vt);
  k_flash<<<dim3(NCHUNK, 16, A_N), 256, 0, stream>>>(kn, vt, qn, counts, lists, acc, sume);
  k_loss<<<512, 256, 0, stream>>>(acc, sume, nxt, loss);
  k_final<<<1, 1, 0, stream>>>(loss, (float*)d_out);
}

// Round 3
// 476.352 us; speedup vs baseline: 1.6109x; 1.6109x over previous
//
#include <hip/hip_runtime.h>
#include <stdint.h>

#define B_N 2048
#define Z_N 128
#define A_N 4
#define D_N 50000
#define EPS_F 1e-8f

typedef __attribute__((ext_vector_type(8))) short short8;
typedef __attribute__((ext_vector_type(4))) float f32x4;

__device__ __forceinline__ unsigned short f2bf(float f) {
  unsigned int u = __builtin_bit_cast(unsigned int, f);
  u += 0x7FFFu + ((u >> 16) & 1u);   // RNE
  return (unsigned short)(u >> 16);
}

// ------------------------------------------------------------------
// P1: normalize batch_x rows, route samples into per-action lists
// ------------------------------------------------------------------
__global__ void k_qnorm_route(const float* __restrict__ x, const int* __restrict__ act,
                              float* __restrict__ qn, int* __restrict__ counts,
                              int* __restrict__ lists) {
  int w = threadIdx.x >> 6, lane = threadIdx.x & 63;
  int row = blockIdx.x * 4 + w;                 // < 2048
  const float2 v = ((const float2*)(x + (size_t)row * Z_N))[lane];
  float ss = v.x * v.x + v.y * v.y;
#pragma unroll
  for (int m = 1; m < 64; m <<= 1) ss += __shfl_xor(ss, m);
  float inv = 1.0f / (sqrtf(ss) + EPS_F);
  float2 o; o.x = v.x * inv; o.y = v.y * inv;
  ((float2*)(qn + (size_t)row * Z_N))[lane] = o;
  if (lane == 0) {
    int a = act[row];
    int pos = atomicAdd(&counts[a], 1);
    lists[a * B_N + pos] = row;
  }
}

// ------------------------------------------------------------------
// P2: normalize keys rows -> bf16 Kn[a][d][z]
// ------------------------------------------------------------------
__global__ void k_keynorm(const float* __restrict__ keys, unsigned short* __restrict__ kn) {
  int w = threadIdx.x >> 6, lane = threadIdx.x & 63;
  size_t row = (size_t)blockIdx.x * 4 + w;      // < A*D = 200000
  const float2 v = ((const float2*)(keys + row * Z_N))[lane];
  float ss = v.x * v.x + v.y * v.y;
#pragma unroll
  for (int m = 1; m < 64; m <<= 1) ss += __shfl_xor(ss, m);
  float inv = 1.0f / (sqrtf(ss) + EPS_F);
  unsigned int packed = ((unsigned int)f2bf(v.y * inv) << 16) | f2bf(v.x * inv);
  ((unsigned int*)(kn + row * Z_N))[lane] = packed;
}

// ------------------------------------------------------------------
// P3: transpose vals -> bf16 Vt[a][z][d]
// ------------------------------------------------------------------
__global__ void k_vtrans(const float* __restrict__ vals, unsigned short* __restrict__ vt) {
  __shared__ float tile[64][65];
  int a = blockIdx.z, d0 = blockIdx.x * 64, z0 = blockIdx.y * 64;
  int t = threadIdx.x;
  int r = t >> 4, c4 = (t & 15) * 4;
#pragma unroll
  for (int i = 0; i < 4; ++i) {
    int dr = r + i * 16, d = d0 + dr;
    if (d < D_N) {
      const float4 v = *(const float4*)(vals + ((size_t)a * D_N + d) * Z_N + z0 + c4);
      tile[dr][c4 + 0] = v.x; tile[dr][c4 + 1] = v.y;
      tile[dr][c4 + 2] = v.z; tile[dr][c4 + 3] = v.w;
    }
  }
  __syncthreads();
  int zz = t >> 2, dg = (t & 3) * 16;
  if (d0 + dg < D_N) {
    union { unsigned short u[16]; uint4 q[2]; } pk;
#pragma unroll
    for (int j = 0; j < 16; ++j) pk.u[j] = f2bf(tile[dg + j][zz]);
    unsigned short* dst = vt + ((size_t)a * Z_N + z0 + zz) * D_N + d0 + dg;
    ((uint4*)dst)[0] = pk.q[0];
    ((uint4*)dst)[1] = pk.q[1];
  }
}

// ------------------------------------------------------------------
// F: routed flash attention, bf16 MFMA 16x16x32, chunked over D.
//    63 chunks x ~4 tiles x 4 actions -> ~1008 active blocks (~4/CU).
//    Register double-buffer prefetch overlaps next tile's global loads
//    with current tile's compute.
//    LDS strides: Kl=140 shorts (bank step 6 -> 2-way, free),
//    Vl/Pl=36 shorts (bank step 18 -> 2-way, free).
//    launch_bounds(256,2): (256,4) forced VGPR=64 -> spill catastrophe (r2).
// ------------------------------------------------------------------
#define TILE_B 128
#define KT 32
#define CHUNK 800    // 25*32 ; 63 chunks cover 50400 >= D
#define NITER 25
#define NCHUNK 63
#define KL_S 140
#define VL_S 36

__launch_bounds__(256, 2)
__global__ void k_flash(const unsigned short* __restrict__ kn,
                        const unsigned short* __restrict__ vt,
                        const float* __restrict__ qn,
                        const int* __restrict__ counts,
                        const int* __restrict__ lists,
                        float* __restrict__ acc,
                        float* __restrict__ sume) {
  int a = blockIdx.z, ty = blockIdx.y;
  int nb = counts[a];
  if (ty * TILE_B >= nb) return;

  __shared__ unsigned short Kl[KT * KL_S];      // [key][z]
  __shared__ unsigned short Vl[128 * VL_S];     // [z][key]
  __shared__ unsigned short Pl[4][32 * VL_S];   // per-wave P tile [sample][key]

  int t = threadIdx.x;
  int w = t >> 6, lane = t & 63;
  int lq = lane >> 4, ln = lane & 15;

  const unsigned short* kn_a = kn + (size_t)a * D_N * Z_N;
  const unsigned short* vt_a = vt + (size_t)a * Z_N * D_N;
  const int* list_a = lists + a * B_N;

  // Q fragments: A-layout, lane holds Q[sample=ln][z = c*32 + lq*8 + j]
  short8 qf[2][4];
#pragma unroll
  for (int mt = 0; mt < 2; ++mt) {
    int g = ty * TILE_B + w * 32 + mt * 16 + ln;
    bool valid = g < nb;
    int si = valid ? list_a[g] : 0;
#pragma unroll
    for (int c = 0; c < 4; ++c) {
      float4 f0 = {0.f, 0.f, 0.f, 0.f}, f1 = {0.f, 0.f, 0.f, 0.f};
      if (valid) {
        const float* qp = qn + (size_t)si * Z_N + c * 32 + lq * 8;
        f0 = *(const float4*)qp;
        f1 = *(const float4*)(qp + 4);
      }
      short8 s;
      s[0] = (short)f2bf(f0.x); s[1] = (short)f2bf(f0.y);
      s[2] = (short)f2bf(f0.z); s[3] = (short)f2bf(f0.w);
      s[4] = (short)f2bf(f1.x); s[5] = (short)f2bf(f1.y);
      s[6] = (short)f2bf(f1.z); s[7] = (short)f2bf(f1.w);
      qf[mt][c] = s;
    }
  }

  f32x4 O[2][8];
#pragma unroll
  for (int mt = 0; mt < 2; ++mt)
#pragma unroll
    for (int zt = 0; zt < 8; ++zt) O[mt][zt] = (f32x4){0.f, 0.f, 0.f, 0.f};
  float rs[2][4] = {{0.f, 0.f, 0.f, 0.f}, {0.f, 0.f, 0.f, 0.f}};

  int d_base = blockIdx.x * CHUNK;
  int sk_key = t >> 3, sk_z = (t & 7) * 16;     // K staging: 32B per thread
  int sv_z = t >> 1, sv_k = (t & 1) * 16;       // V staging: 32B per thread

  const uint4 z4 = {0u, 0u, 0u, 0u};
  uint4 kA, kB, vA, vB;

  // prefetch tile 0
  {
    int key = d_base + sk_key;
    bool kok = key < D_N;
    const uint4* ksrc = (const uint4*)(kn_a + (size_t)key * Z_N + sk_z);
    kA = kok ? ksrc[0] : z4;
    kB = kok ? ksrc[1] : z4;
    int kk = d_base + sv_k;
    const unsigned short* vsrc = vt_a + (size_t)sv_z * D_N + kk;
    vA = (kk < D_N)     ? *(const uint4*)vsrc       : z4;
    vB = (kk + 8 < D_N) ? *(const uint4*)(vsrc + 8) : z4;
  }

  for (int kt = 0; kt < NITER; ++kt) {
    int d0 = d_base + kt * KT;
    __syncthreads();                            // prev iter's LDS reads done
    {   // commit prefetched tile to LDS
      uint4* kd = (uint4*)&Kl[sk_key * KL_S + sk_z];
      kd[0] = kA; kd[1] = kB;
      uint4* vd = (uint4*)&Vl[sv_z * VL_S + sv_k];
      vd[0] = vA; vd[1] = vB;
    }
    __syncthreads();
    if (kt + 1 < NITER) {                       // issue next tile's loads NOW
      int d1 = d0 + KT;
      int key = d1 + sk_key;
      bool kok = key < D_N;
      const uint4* ksrc = (const uint4*)(kn_a + (size_t)key * Z_N + sk_z);
      kA = kok ? ksrc[0] : z4;
      kB = kok ? ksrc[1] : z4;
      int kk = d1 + sv_k;
      const unsigned short* vsrc = vt_a + (size_t)sv_z * D_N + kk;
      vA = (kk < D_N)     ? *(const uint4*)vsrc       : z4;
      vB = (kk + 8 < D_N) ? *(const uint4*)(vsrc + 8) : z4;
    }

    // S = Qn . Kn^T   (M=16 samples, N=16 keys, K=Z accumulated over 4 chunks)
    f32x4 S[2][2];
#pragma unroll
    for (int nt = 0; nt < 2; ++nt) {
      short8 kf[4];
#pragma unroll
      for (int c = 0; c < 4; ++c)
        kf[c] = *(const short8*)&Kl[(nt * 16 + ln) * KL_S + c * 32 + lq * 8];
#pragma unroll
      for (int mt = 0; mt < 2; ++mt) {
        f32x4 s4 = (f32x4){0.f, 0.f, 0.f, 0.f};
#pragma unroll
        for (int c = 0; c < 4; ++c)
          s4 = __builtin_amdgcn_mfma_f32_16x16x32_bf16(qf[mt][c], kf[c], s4, 0, 0, 0);
        S[mt][nt] = s4;
      }
    }

    // exp (no max-sub needed: |sim|<=~1), rowsum partials, P -> LDS (C->A layout)
#pragma unroll
    for (int mt = 0; mt < 2; ++mt)
#pragma unroll
      for (int nt = 0; nt < 2; ++nt) {
        bool kv = (d0 + nt * 16 + ln) < D_N;
#pragma unroll
        for (int r = 0; r < 4; ++r) {
          float e = kv ? __expf(S[mt][nt][r]) : 0.f;
          rs[mt][r] += e;
          Pl[w][(mt * 16 + lq * 4 + r) * VL_S + nt * 16 + ln] = f2bf(e);
        }
      }

    // O += P . V
    short8 pf0 = *(const short8*)&Pl[w][(ln) * VL_S + lq * 8];
    short8 pf1 = *(const short8*)&Pl[w][(16 + ln) * VL_S + lq * 8];
#pragma unroll
    for (int zt = 0; zt < 8; ++zt) {
      short8 vf = *(const short8*)&Vl[(zt * 16 + ln) * VL_S + lq * 8];
      O[0][zt] = __builtin_amdgcn_mfma_f32_16x16x32_bf16(pf0, vf, O[0][zt], 0, 0, 0);
      O[1][zt] = __builtin_amdgcn_mfma_f32_16x16x32_bf16(pf1, vf, O[1][zt], 0, 0, 0);
    }
  }

  // full rowsums: reduce over the 16 lanes of each quad-group
#pragma unroll
  for (int mt = 0; mt < 2; ++mt)
#pragma unroll
    for (int r = 0; r < 4; ++r) {
      float v = rs[mt][r];
      v += __shfl_xor(v, 1); v += __shfl_xor(v, 2);
      v += __shfl_xor(v, 4); v += __shfl_xor(v, 8);
      rs[mt][r] = v;
    }

  // scatter partials: C-layout rows = lq*4+r, col z = ln
#pragma unroll
  for (int mt = 0; mt < 2; ++mt)
#pragma unroll
    for (int r = 0; r < 4; ++r) {
      int g = ty * TILE_B + w * 32 + mt * 16 + lq * 4 + r;
      if (g < nb) {
        int si = list_a[g];
        float* arow = acc + (size_t)si * Z_N + ln;
#pragma unroll
        for (int zt = 0; zt < 8; ++zt) atomicAdd(arow + zt * 16, O[mt][zt][r]);
        if (ln == 0) atomicAdd(&sume[si], rs[mt][r]);
      }
    }
}

// ------------------------------------------------------------------
// F2: pred = acc/sume, accumulate sum of squared error (1 atomic/block)
// ------------------------------------------------------------------
__global__ void k_loss(const float* __restrict__ acc, const float* __restrict__ sume,
                       const float* __restrict__ nxt, float* __restrict__ loss) {
  __shared__ float ls[4];
  int w = threadIdx.x >> 6, lane = threadIdx.x & 63;
  int row = blockIdx.x * 4 + w;
  float inv = 1.0f / sume[row];
  const float2 p2 = ((const float2*)(acc + (size_t)row * Z_N))[lane];
  const float2 n2 = ((const float2*)(nxt + (size_t)row * Z_N))[lane];
  float dx = p2.x * inv - n2.x, dy = p2.y * inv - n2.y;
  float s = dx * dx + dy * dy;
#pragma unroll
  for (int m = 1; m < 64; m <<= 1) s += __shfl_xor(s, m);
  if (lane == 0) ls[w] = s;
  __syncthreads();
  if (threadIdx.x == 0) atomicAdd(loss, ls[0] + ls[1] + ls[2] + ls[3]);
}

__global__ void k_final(const float* __restrict__ loss, float* __restrict__ out) {
  out[0] = loss[0] * (1.0f / (float)(B_N * Z_N));
}

// ------------------------------------------------------------------
// ws layout (bytes):
//  qn      @ 0          1,048,576
//  acc     @ 1,048,576  1,048,576   (zeroed)
//  sume    @ 2,097,152      8,192   (zeroed)
//  counts  @ 2,105,344         16   (zeroed)
//  loss    @ 2,105,360         16   (zeroed)
//  lists   @ 2,105,376     32,768
//  Kn bf16 @ 2,138,368 51,200,000
//  Vt bf16 @ 53,338,368 51,200,000   -> total ~104.5 MB
// ------------------------------------------------------------------
extern "C" void kernel_launch(void* const* d_in, const int* in_sizes, int n_in,
                              void* d_out, int out_size, void* d_ws, size_t ws_size,
                              hipStream_t stream) {
  const float* x    = (const float*)d_in[0];
  const float* nxt  = (const float*)d_in[1];
  const float* keys = (const float*)d_in[2];
  const float* vals = (const float*)d_in[3];
  const int*   act  = (const int*)d_in[4];

  char* ws = (char*)d_ws;
  float* qn     = (float*)(ws + 0);
  float* acc    = (float*)(ws + 1048576);
  float* sume   = (float*)(ws + 2097152);
  int*   counts = (int*)(ws + 2105344);
  float* loss   = (float*)(ws + 2105360);
  int*   lists  = (int*)(ws + 2105376);
  unsigned short* kn = (unsigned short*)(ws + 2138368);
  unsigned short* vt = (unsigned short*)(ws + 53338368);

  hipMemsetAsync(ws + 1048576, 0, 1056800, stream);

  k_qnorm_route<<<512, 256, 0, stream>>>(x, act, qn, counts, lists);
  k_keynorm<<<50000, 256, 0, stream>>>(keys, kn);
  k_vtrans<<<dim3(782, 2, A_N), 256, 0, stream>>>(vals, vt);
  k_flash<<<dim3(NCHUNK, 16, A_N), 256, 0, stream>>>(kn, vt, qn, counts, lists, acc, sume);
  k_loss<<<512, 256, 0, stream>>>(acc, sume, nxt, loss);
  k_final<<<1, 1, 0, stream>>>(loss, (float*)d_out);
}

// Round 4
// 452.825 us; speedup vs baseline: 1.6946x; 1.0520x over previous
//
#include <hip/hip_runtime.h>
#include <stdint.h>

#define B_N 2048
#define Z_N 128
#define A_N 4
#define D_N 50000
#define EPS_F 1e-8f

typedef __attribute__((ext_vector_type(8))) short short8;   // 8 bf16 (4 VGPRs)
typedef __attribute__((ext_vector_type(4))) short bf4;      // 4 bf16 (2 VGPRs)
typedef __attribute__((ext_vector_type(4))) float f32x4;

__device__ __forceinline__ unsigned short f2bf(float f) {
  unsigned int u = __builtin_bit_cast(unsigned int, f);
  u += 0x7FFFu + ((u >> 16) & 1u);   // RNE
  return (unsigned short)(u >> 16);
}

// ------------------------------------------------------------------
// P1: normalize keys rows -> bf16 kn[a][d][z]; rows >= 200000 are
//     batch_x rows -> bf16 qnb + routing (fused, saves one launch)
// ------------------------------------------------------------------
__global__ void k_norm(const float* __restrict__ keys, const float* __restrict__ x,
                       const int* __restrict__ act,
                       unsigned short* __restrict__ kn, unsigned short* __restrict__ qnb,
                       int* __restrict__ counts, int* __restrict__ lists) {
  int w = threadIdx.x >> 6, lane = threadIdx.x & 63;
  size_t row = (size_t)blockIdx.x * 4 + w;      // < 202048
  bool isq = row >= (size_t)A_N * D_N;
  size_t r = isq ? row - (size_t)A_N * D_N : row;
  const float* src = (isq ? x : keys) + r * Z_N;
  const float2 v = ((const float2*)src)[lane];
  float ss = v.x * v.x + v.y * v.y;
#pragma unroll
  for (int m = 1; m < 64; m <<= 1) ss += __shfl_xor(ss, m);
  float inv = 1.0f / (sqrtf(ss) + EPS_F);
  unsigned int packed = ((unsigned int)f2bf(v.y * inv) << 16) | f2bf(v.x * inv);
  unsigned short* dst = (isq ? qnb : kn) + r * Z_N;
  ((unsigned int*)dst)[lane] = packed;
  if (isq && lane == 0) {
    int a = act[r];
    int pos = atomicAdd(&counts[a], 1);
    lists[a * B_N + pos] = (int)r;
  }
}

// ------------------------------------------------------------------
// P2: transpose vals -> bf16 Vt[a][z][d]
// ------------------------------------------------------------------
__global__ void k_vtrans(const float* __restrict__ vals, unsigned short* __restrict__ vt) {
  __shared__ float tile[64][65];
  int a = blockIdx.z, d0 = blockIdx.x * 64, z0 = blockIdx.y * 64;
  int t = threadIdx.x;
  int r = t >> 4, c4 = (t & 15) * 4;
#pragma unroll
  for (int i = 0; i < 4; ++i) {
    int dr = r + i * 16, d = d0 + dr;
    if (d < D_N) {
      const float4 v = *(const float4*)(vals + ((size_t)a * D_N + d) * Z_N + z0 + c4);
      tile[dr][c4 + 0] = v.x; tile[dr][c4 + 1] = v.y;
      tile[dr][c4 + 2] = v.z; tile[dr][c4 + 3] = v.w;
    }
  }
  __syncthreads();
  int zz = t >> 2, dg = (t & 3) * 16;
  if (d0 + dg < D_N) {
    union { unsigned short u[16]; uint4 q[2]; } pk;
#pragma unroll
    for (int j = 0; j < 16; ++j) pk.u[j] = f2bf(tile[dg + j][zz]);
    unsigned short* dst = vt + ((size_t)a * Z_N + z0 + zz) * D_N + d0 + dg;
    ((uint4*)dst)[0] = pk.q[0];
    ((uint4*)dst)[1] = pk.q[1];
  }
}

// ------------------------------------------------------------------
// W: build exact work list (a, ty, chunk), chunk-major for L2 locality.
//    work[0] = total; work[1+i] = a | ty<<2 | chunk<<8. Max 63*20=1260.
// ------------------------------------------------------------------
#define TILE_B 128
#define KT 32
#define CHUNK 800    // 25*32 ; 63 chunks cover 50400 >= D
#define NITER 25
#define NCHUNK 63
#define KL_S 140     // bank step 6 -> 2-way (free)
#define VL_S 36      // bank step 18 -> 2-way (free)

__global__ void k_worklist(const int* __restrict__ counts, int* __restrict__ work) {
  int t0 = (counts[0] + TILE_B - 1) / TILE_B;
  int t1 = (counts[1] + TILE_B - 1) / TILE_B;
  int t2 = (counts[2] + TILE_B - 1) / TILE_B;
  int t3 = (counts[3] + TILE_B - 1) / TILE_B;
  int T = t0 + t1 + t2 + t3;
  int total = T * NCHUNK;
  if (threadIdx.x == 0) work[0] = total;
  for (int i = threadIdx.x; i < total; i += 256) {
    int c = i / T, j = i - c * T;
    int a, ty;
    if (j < t0)                { a = 0; ty = j; }
    else if (j < t0 + t1)      { a = 1; ty = j - t0; }
    else if (j < t0 + t1 + t2) { a = 2; ty = j - t0 - t1; }
    else                       { a = 3; ty = j - t0 - t1 - t2; }
    work[1 + i] = a | (ty << 2) | (c << 8);
  }
}

// ------------------------------------------------------------------
// F: routed flash attention. S^T = K.Q^T via 16x16x32 MFMA; its C-layout
//    (lane=sample col, rows=keys lq*4+r) IS the x16 A-frag layout, so P
//    feeds v_mfma_f32_16x16x16_bf16 PV directly — no LDS round-trip.
// ------------------------------------------------------------------
__launch_bounds__(256, 2)
__global__ void k_flash(const unsigned short* __restrict__ kn,
                        const unsigned short* __restrict__ vt,
                        const unsigned short* __restrict__ qnb,
                        const int* __restrict__ counts,
                        const int* __restrict__ lists,
                        const int* __restrict__ work,
                        float* __restrict__ acc,
                        float* __restrict__ sume) {
  int total = work[0];
  if ((int)blockIdx.x >= total) return;
  int wi = work[1 + blockIdx.x];
  int a = wi & 3, ty = (wi >> 2) & 63, chunk = wi >> 8;
  int nb = counts[a];

  __shared__ unsigned short Kl[KT * KL_S];      // [key][z]
  __shared__ unsigned short Vl[128 * VL_S];     // [z][key]

  int t = threadIdx.x;
  int w = t >> 6, lane = t & 63;
  int lq = lane >> 4, ln = lane & 15;

  const unsigned short* kn_a = kn + (size_t)a * D_N * Z_N;
  const unsigned short* vt_a = vt + (size_t)a * Z_N * D_N;
  const int* list_a = lists + a * B_N;

  // Q fragments (bf16 direct): lane holds Q[sample=ln][z = c*32 + lq*8 + j]
  short8 qf[2][4];
#pragma unroll
  for (int mt = 0; mt < 2; ++mt) {
    int g = ty * TILE_B + w * 32 + mt * 16 + ln;
    bool valid = g < nb;
    int si = valid ? list_a[g] : 0;
#pragma unroll
    for (int c = 0; c < 4; ++c) {
      short8 s = (short8){0,0,0,0,0,0,0,0};
      if (valid) s = *(const short8*)(qnb + (size_t)si * Z_N + c * 32 + lq * 8);
      qf[mt][c] = s;
    }
  }

  f32x4 O[2][8];
#pragma unroll
  for (int mt = 0; mt < 2; ++mt)
#pragma unroll
    for (int zt = 0; zt < 8; ++zt) O[mt][zt] = (f32x4){0.f, 0.f, 0.f, 0.f};
  float rs[2] = {0.f, 0.f};                     // per-lane: sample = ln of tile mt

  int d_base = chunk * CHUNK;
  int sk_key = t >> 3, sk_z = (t & 7) * 16;     // K staging: 32B per thread
  int sv_z = t >> 1, sv_k = (t & 1) * 16;       // V staging: 32B per thread

  const uint4 z4 = {0u, 0u, 0u, 0u};
  uint4 kA, kB, vA, vB;

  // prefetch tile 0
  {
    int key = d_base + sk_key;
    bool kok = key < D_N;
    const uint4* ksrc = (const uint4*)(kn_a + (size_t)key * Z_N + sk_z);
    kA = kok ? ksrc[0] : z4;
    kB = kok ? ksrc[1] : z4;
    int kk = d_base + sv_k;
    const unsigned short* vsrc = vt_a + (size_t)sv_z * D_N + kk;
    vA = (kk < D_N)     ? *(const uint4*)vsrc       : z4;
    vB = (kk + 8 < D_N) ? *(const uint4*)(vsrc + 8) : z4;
  }

  for (int kt = 0; kt < NITER; ++kt) {
    int d0 = d_base + kt * KT;
    __syncthreads();                            // prev iter's LDS reads done
    {   // commit prefetched tile to LDS
      uint4* kd = (uint4*)&Kl[sk_key * KL_S + sk_z];
      kd[0] = kA; kd[1] = kB;
      uint4* vd = (uint4*)&Vl[sv_z * VL_S + sv_k];
      vd[0] = vA; vd[1] = vB;
    }
    __syncthreads();
    if (kt + 1 < NITER) {                       // issue next tile's loads NOW
      int d1 = d0 + KT;
      int key = d1 + sk_key;
      bool kok = key < D_N;
      const uint4* ksrc = (const uint4*)(kn_a + (size_t)key * Z_N + sk_z);
      kA = kok ? ksrc[0] : z4;
      kB = kok ? ksrc[1] : z4;
      int kk = d1 + sv_k;
      const unsigned short* vsrc = vt_a + (size_t)sv_z * D_N + kk;
      vA = (kk < D_N)     ? *(const uint4*)vsrc       : z4;
      vB = (kk + 8 < D_N) ? *(const uint4*)(vsrc + 8) : z4;
    }

    // S^T[key][sample] = Kn . Qn^T  (A=kf, B=qf; same register contents)
    f32x4 ST[2][2];                             // [nt key-tile][mt sample-tile]
#pragma unroll
    for (int nt = 0; nt < 2; ++nt) {
      short8 kf[4];
#pragma unroll
      for (int c = 0; c < 4; ++c)
        kf[c] = *(const short8*)&Kl[(nt * 16 + ln) * KL_S + c * 32 + lq * 8];
#pragma unroll
      for (int mt = 0; mt < 2; ++mt) {
        f32x4 s4 = (f32x4){0.f, 0.f, 0.f, 0.f};
#pragma unroll
        for (int c = 0; c < 4; ++c)
          s4 = __builtin_amdgcn_mfma_f32_16x16x32_bf16(kf[c], qf[mt][c], s4, 0, 0, 0);
        ST[nt][mt] = s4;
      }
    }

    // exp + mask, per-lane rowsum (sample=ln), pack into x16 A-frags:
    // pf[mt][nt] holds P[sample=ln][key = nt*16 + lq*4 + (reg*2+h)]
    bf4 pf[2][2];
#pragma unroll
    for (int nt = 0; nt < 2; ++nt) {
      int kbase = d0 + nt * 16 + lq * 4;
#pragma unroll
      for (int mt = 0; mt < 2; ++mt) {
        float e0 = (kbase + 0) < D_N ? __expf(ST[nt][mt][0]) : 0.f;
        float e1 = (kbase + 1) < D_N ? __expf(ST[nt][mt][1]) : 0.f;
        float e2 = (kbase + 2) < D_N ? __expf(ST[nt][mt][2]) : 0.f;
        float e3 = (kbase + 3) < D_N ? __expf(ST[nt][mt][3]) : 0.f;
        rs[mt] += e0 + e1 + e2 + e3;
        unsigned long long p =
            (unsigned long long)f2bf(e0) |
            ((unsigned long long)f2bf(e1) << 16) |
            ((unsigned long long)f2bf(e2) << 32) |
            ((unsigned long long)f2bf(e3) << 48);
        pf[mt][nt] = __builtin_bit_cast(bf4, p);
      }
    }

    // O += P . V  via x16 MFMA; B-frag: V[key=nt*16+lq*4+j][z=zt*16+ln]
#pragma unroll
    for (int zt = 0; zt < 8; ++zt) {
#pragma unroll
      for (int nt = 0; nt < 2; ++nt) {
        bf4 vf = *(const bf4*)&Vl[(zt * 16 + ln) * VL_S + nt * 16 + lq * 4];
        asm volatile("s_nop 1\n\tv_mfma_f32_16x16x16_bf16 %0, %1, %2, %0"
                     : "+v"(O[0][zt]) : "v"(pf[0][nt]), "v"(vf));
        asm volatile("s_nop 1\n\tv_mfma_f32_16x16x16_bf16 %0, %1, %2, %0"
                     : "+v"(O[1][zt]) : "v"(pf[1][nt]), "v"(vf));
      }
    }
  }

  // rowsum finalize: lanes (lq, ln) all hold partial for sample ln -> cross-quad
#pragma unroll
  for (int mt = 0; mt < 2; ++mt) {
    float v = rs[mt];
    v += __shfl_xor(v, 16);
    v += __shfl_xor(v, 32);
    rs[mt] = v;
  }

  // scatter: O C-layout rows = sample lq*4+r, col z = zt*16+ln
#pragma unroll
  for (int mt = 0; mt < 2; ++mt) {
    if (lq == 0) {                              // one lane per sample for sume
      int g = ty * TILE_B + w * 32 + mt * 16 + ln;
      if (g < nb) atomicAdd(&sume[list_a[g]], rs[mt]);
    }
#pragma unroll
    for (int r = 0; r < 4; ++r) {
      int g = ty * TILE_B + w * 32 + mt * 16 + lq * 4 + r;
      if (g < nb) {
        int si = list_a[g];
        float* arow = acc + (size_t)si * Z_N + ln;
#pragma unroll
        for (int zt = 0; zt < 8; ++zt) atomicAdd(arow + zt * 16, O[mt][zt][r]);
      }
    }
  }
}

// ------------------------------------------------------------------
// F2: pred = acc/sume, accumulate sum of squared error (1 atomic/block)
// ------------------------------------------------------------------
__global__ void k_loss(const float* __restrict__ acc, const float* __restrict__ sume,
                       const float* __restrict__ nxt, float* __restrict__ loss) {
  __shared__ float ls[4];
  int w = threadIdx.x >> 6, lane = threadIdx.x & 63;
  int row = blockIdx.x * 4 + w;
  float inv = 1.0f / sume[row];
  const float2 p2 = ((const float2*)(acc + (size_t)row * Z_N))[lane];
  const float2 n2 = ((const float2*)(nxt + (size_t)row * Z_N))[lane];
  float dx = p2.x * inv - n2.x, dy = p2.y * inv - n2.y;
  float s = dx * dx + dy * dy;
#pragma unroll
  for (int m = 1; m < 64; m <<= 1) s += __shfl_xor(s, m);
  if (lane == 0) ls[w] = s;
  __syncthreads();
  if (threadIdx.x == 0) atomicAdd(loss, ls[0] + ls[1] + ls[2] + ls[3]);
}

__global__ void k_final(const float* __restrict__ loss, float* __restrict__ out) {
  out[0] = loss[0] * (1.0f / (float)(B_N * Z_N));
}

// ------------------------------------------------------------------
// ws layout (bytes):
//  qnb bf16 @ 0          524,288
//  acc      @ 1,048,576  1,048,576   (zeroed)
//  sume     @ 2,097,152      8,192   (zeroed)
//  counts   @ 2,105,344         16   (zeroed)
//  loss     @ 2,105,360         16   (zeroed)
//  lists    @ 2,105,376     32,768
//  work     @ 2,138,144      8,192
//  Kn bf16  @ 2,146,560 51,200,000
//  Vt bf16  @ 53,346,560 51,200,000  -> total ~104.5 MB
// ------------------------------------------------------------------
extern "C" void kernel_launch(void* const* d_in, const int* in_sizes, int n_in,
                              void* d_out, int out_size, void* d_ws, size_t ws_size,
                              hipStream_t stream) {
  const float* x    = (const float*)d_in[0];
  const float* nxt  = (const float*)d_in[1];
  const float* keys = (const float*)d_in[2];
  const float* vals = (const float*)d_in[3];
  const int*   act  = (const int*)d_in[4];

  char* ws = (char*)d_ws;
  unsigned short* qnb = (unsigned short*)(ws + 0);
  float* acc    = (float*)(ws + 1048576);
  float* sume   = (float*)(ws + 2097152);
  int*   counts = (int*)(ws + 2105344);
  float* loss   = (float*)(ws + 2105360);
  int*   lists  = (int*)(ws + 2105376);
  int*   work   = (int*)(ws + 2138144);
  unsigned short* kn = (unsigned short*)(ws + 2146560);
  unsigned short* vt = (unsigned short*)(ws + 53346560);

  hipMemsetAsync(ws + 1048576, 0, 1056800, stream);

  k_norm<<<50512, 256, 0, stream>>>(keys, x, act, kn, qnb, counts, lists);
  k_vtrans<<<dim3(782, 2, A_N), 256, 0, stream>>>(vals, vt);
  k_worklist<<<1, 256, 0, stream>>>(counts, work);
  k_flash<<<1280, 256, 0, stream>>>(kn, vt, qnb, counts, lists, work, acc, sume);
  k_loss<<<512, 256, 0, stream>>>(acc, sume, nxt, loss);
  k_final<<<1, 1, 0, stream>>>(loss, (float*)d_out);
}

// Round 5
// 421.538 us; speedup vs baseline: 1.8203x; 1.0742x over previous
//
#include <hip/hip_runtime.h>
#include <stdint.h>

#define B_N 2048
#define Z_N 128
#define A_N 4
#define D_N 50000
#define EPS_F 1e-8f

#define TILE_B 128
#define KT 32
#define NSPLIT 32
#define SPAN 1568      // 49*32 ; 32 spans cover 50176 >= D
#define NITER 49
#define KL_S 140       // bank step 6 -> 2-way (free)
#define VL_S 36        // bank step 18 -> ~2-way

typedef __attribute__((ext_vector_type(8))) short short8;   // 8 bf16
typedef __attribute__((ext_vector_type(4))) short bf4;      // 4 bf16
typedef __attribute__((ext_vector_type(4))) float f32x4;

__device__ __forceinline__ unsigned short f2bf(float f) {
  unsigned int u = __builtin_bit_cast(unsigned int, f);
  u += 0x7FFFu + ((u >> 16) & 1u);   // RNE
  return (unsigned short)(u >> 16);
}

// ------------------------------------------------------------------
// P1: normalize keys rows -> bf16 kn[a][d][z]; rows >= 200000 are
//     batch_x rows -> bf16 qnb. (routing moved to k_route)
// ------------------------------------------------------------------
__global__ void k_norm(const float* __restrict__ keys, const float* __restrict__ x,
                       unsigned short* __restrict__ kn, unsigned short* __restrict__ qnb) {
  int w = threadIdx.x >> 6, lane = threadIdx.x & 63;
  size_t row = (size_t)blockIdx.x * 4 + w;      // < 202048
  bool isq = row >= (size_t)A_N * D_N;
  size_t r = isq ? row - (size_t)A_N * D_N : row;
  const float* src = (isq ? x : keys) + r * Z_N;
  const float2 v = ((const float2*)src)[lane];
  float ss = v.x * v.x + v.y * v.y;
#pragma unroll
  for (int m = 1; m < 64; m <<= 1) ss += __shfl_xor(ss, m);
  float inv = 1.0f / (sqrtf(ss) + EPS_F);
  unsigned int packed = ((unsigned int)f2bf(v.y * inv) << 16) | f2bf(v.x * inv);
  unsigned short* dst = (isq ? qnb : kn) + r * Z_N;
  ((unsigned int*)dst)[lane] = packed;
}

// ------------------------------------------------------------------
// P2: transpose vals -> bf16 Vt[a][z][d]
// ------------------------------------------------------------------
__global__ void k_vtrans(const float* __restrict__ vals, unsigned short* __restrict__ vt) {
  __shared__ float tile[64][65];
  int a = blockIdx.z, d0 = blockIdx.x * 64, z0 = blockIdx.y * 64;
  int t = threadIdx.x;
  int r = t >> 4, c4 = (t & 15) * 4;
#pragma unroll
  for (int i = 0; i < 4; ++i) {
    int dr = r + i * 16, d = d0 + dr;
    if (d < D_N) {
      const float4 v = *(const float4*)(vals + ((size_t)a * D_N + d) * Z_N + z0 + c4);
      tile[dr][c4 + 0] = v.x; tile[dr][c4 + 1] = v.y;
      tile[dr][c4 + 2] = v.z; tile[dr][c4 + 3] = v.w;
    }
  }
  __syncthreads();
  int zz = t >> 2, dg = (t & 3) * 16;
  if (d0 + dg < D_N) {
    union { unsigned short u[16]; uint4 q[2]; } pk;
#pragma unroll
    for (int j = 0; j < 16; ++j) pk.u[j] = f2bf(tile[dg + j][zz]);
    unsigned short* dst = vt + ((size_t)a * Z_N + z0 + zz) * D_N + d0 + dg;
    ((uint4*)dst)[0] = pk.q[0];
    ((uint4*)dst)[1] = pk.q[1];
  }
}

// ------------------------------------------------------------------
// R: single-block routing (LDS atomics — no global atomic storm) +
//    work list (a, ty, span), span-major for L2 locality.
// ------------------------------------------------------------------
__global__ void k_route(const int* __restrict__ act, int* __restrict__ counts,
                        int* __restrict__ lists, int* __restrict__ work) {
  __shared__ int lc[4];
  int t = threadIdx.x;
  if (t < 4) lc[t] = 0;
  __syncthreads();
  for (int i = t; i < B_N; i += 1024) {
    int a = act[i];
    int pos = atomicAdd(&lc[a], 1);
    lists[a * B_N + pos] = i;
  }
  __syncthreads();
  if (t < 4) counts[t] = lc[t];
  int t0 = (lc[0] + TILE_B - 1) >> 7, t1 = (lc[1] + TILE_B - 1) >> 7;
  int t2 = (lc[2] + TILE_B - 1) >> 7, t3 = (lc[3] + TILE_B - 1) >> 7;
  int T = t0 + t1 + t2 + t3;
  int total = T * NSPLIT;
  if (t == 0) work[0] = total;
  for (int i = t; i < total; i += 1024) {
    int c = i / T, j = i - c * T;
    int a, ty;
    if (j < t0)                { a = 0; ty = j; }
    else if (j < t0 + t1)      { a = 1; ty = j - t0; }
    else if (j < t0 + t1 + t2) { a = 2; ty = j - t0 - t1; }
    else                       { a = 3; ty = j - t0 - t1 - t2; }
    work[1 + i] = a | (ty << 2) | (c << 8);
  }
}

// ------------------------------------------------------------------
// F: routed flash attention. 512 threads / 8 waves; each wave owns one
//    16-sample M-tile. S^T = K.Q^T (x32 MFMA) -> C-layout == x16 A-frag,
//    P stays in registers. Single-barrier LDS double-buffer pipeline.
// ------------------------------------------------------------------
__launch_bounds__(512)
__global__ void k_flash(const unsigned short* __restrict__ kn,
                        const unsigned short* __restrict__ vt,
                        const unsigned short* __restrict__ qnb,
                        const int* __restrict__ counts,
                        const int* __restrict__ lists,
                        const int* __restrict__ work,
                        float* __restrict__ acc,
                        float* __restrict__ sume) {
  int total = work[0];
  if ((int)blockIdx.x >= total) return;
  int wi = work[1 + blockIdx.x];
  int a = wi & 3, ty = (wi >> 2) & 63, span = wi >> 8;
  int nb = counts[a];

  __shared__ unsigned short Kl[2][KT * KL_S];    // [buf][key][z]
  __shared__ unsigned short Vl[2][128 * VL_S];   // [buf][z][key]

  int t = threadIdx.x;
  int w = t >> 6, lane = t & 63;
  int lq = lane >> 4, ln = lane & 15;

  const unsigned short* kn_a = kn + (size_t)a * D_N * Z_N;
  const unsigned short* vt_a = vt + (size_t)a * Z_N * D_N;
  const int* list_a = lists + a * B_N;

  // Q fragment: lane holds Q[sample=ln][z = c*32 + lq*8 + j]
  int g0 = ty * TILE_B + w * 16 + ln;
  bool qvalid = g0 < nb;
  int si0 = qvalid ? list_a[g0] : 0;
  short8 qf[4];
#pragma unroll
  for (int c = 0; c < 4; ++c) {
    short8 s = (short8){0,0,0,0,0,0,0,0};
    if (qvalid) s = *(const short8*)(qnb + (size_t)si0 * Z_N + c * 32 + lq * 8);
    qf[c] = s;
  }

  f32x4 O[8];
#pragma unroll
  for (int zt = 0; zt < 8; ++zt) O[zt] = (f32x4){0.f, 0.f, 0.f, 0.f};
  float rs = 0.f;

  int d_base = span * SPAN;
  int sk_key = t >> 4, sk_z = (t & 15) * 8;      // K staging: 16B/thread
  int sv_z = t >> 2, sv_k = (t & 3) * 8;         // V staging: 16B/thread

  const uint4 z4 = {0u, 0u, 0u, 0u};
  uint4 kp, vp;

#define LOAD_TILE(d)                                                          \
  {                                                                           \
    int key = (d) + sk_key;                                                   \
    kp = (key < D_N) ? *(const uint4*)(kn_a + (size_t)key * Z_N + sk_z) : z4; \
    int kk = (d) + sv_k;                                                      \
    vp = (kk < D_N) ? *(const uint4*)(vt_a + (size_t)sv_z * D_N + kk) : z4;   \
  }
#define STORE_TILE(p)                                                         \
  {                                                                           \
    *(uint4*)&Kl[p][sk_key * KL_S + sk_z] = kp;                               \
    *(uint4*)&Vl[p][sv_z * VL_S + sv_k] = vp;                                 \
  }

  LOAD_TILE(d_base);
  STORE_TILE(0);
  LOAD_TILE(d_base + KT);
  __syncthreads();

  int p = 0;
  for (int kt = 0; kt < NITER; ++kt) {
    int d0 = d_base + kt * KT;
    if (kt + 1 < NITER) {
      STORE_TILE(p ^ 1);                         // commit tile kt+1
      if (kt + 2 < NITER) LOAD_TILE(d0 + 2 * KT) // issue tile kt+2
    }

    // S^T[key][sample] = Kn . Qn^T
    f32x4 ST[2];
#pragma unroll
    for (int nt = 0; nt < 2; ++nt) {
      short8 kf[4];
#pragma unroll
      for (int c = 0; c < 4; ++c)
        kf[c] = *(const short8*)&Kl[p][(nt * 16 + ln) * KL_S + c * 32 + lq * 8];
      f32x4 s4 = (f32x4){0.f, 0.f, 0.f, 0.f};
#pragma unroll
      for (int c = 0; c < 4; ++c)
        s4 = __builtin_amdgcn_mfma_f32_16x16x32_bf16(kf[c], qf[c], s4, 0, 0, 0);
      ST[nt] = s4;
    }

    // exp + mask; per-lane rowsum (sample=ln); pack x16 A-frags
    bf4 pf[2];
#pragma unroll
    for (int nt = 0; nt < 2; ++nt) {
      int kbase = d0 + nt * 16 + lq * 4;
      float e0 = (kbase + 0) < D_N ? __expf(ST[nt][0]) : 0.f;
      float e1 = (kbase + 1) < D_N ? __expf(ST[nt][1]) : 0.f;
      float e2 = (kbase + 2) < D_N ? __expf(ST[nt][2]) : 0.f;
      float e3 = (kbase + 3) < D_N ? __expf(ST[nt][3]) : 0.f;
      rs += e0 + e1 + e2 + e3;
      unsigned long long pk =
          (unsigned long long)f2bf(e0) |
          ((unsigned long long)f2bf(e1) << 16) |
          ((unsigned long long)f2bf(e2) << 32) |
          ((unsigned long long)f2bf(e3) << 48);
      pf[nt] = __builtin_bit_cast(bf4, pk);
    }

    // O += P . V  via x16 MFMA; B-frag: V[key=nt*16+lq*4+j][z=zt*16+ln]
#pragma unroll
    for (int zt = 0; zt < 8; ++zt) {
#pragma unroll
      for (int nt = 0; nt < 2; ++nt) {
        bf4 vf = *(const bf4*)&Vl[p][(zt * 16 + ln) * VL_S + nt * 16 + lq * 4];
        asm volatile("s_nop 1\n\tv_mfma_f32_16x16x16_bf16 %0, %1, %2, %0"
                     : "+v"(O[zt]) : "v"(pf[nt]), "v"(vf));
      }
    }

    __syncthreads();
    p ^= 1;
  }

  // rowsum finalize across the 4 quads (all hold partials for sample ln)
  rs += __shfl_xor(rs, 16);
  rs += __shfl_xor(rs, 32);

  if (lq == 0 && qvalid) atomicAdd(&sume[si0], rs);
#pragma unroll
  for (int r = 0; r < 4; ++r) {
    int g = ty * TILE_B + w * 16 + lq * 4 + r;
    if (g < nb) {
      int si = list_a[g];
      float* arow = acc + (size_t)si * Z_N + ln;
#pragma unroll
      for (int zt = 0; zt < 8; ++zt) atomicAdd(arow + zt * 16, O[zt][r]);
    }
  }
}

// ------------------------------------------------------------------
// F2: pred = acc/sume, accumulate sum of squared error (1 atomic/block)
// ------------------------------------------------------------------
__global__ void k_loss(const float* __restrict__ acc, const float* __restrict__ sume,
                       const float* __restrict__ nxt, float* __restrict__ loss) {
  __shared__ float ls[4];
  int w = threadIdx.x >> 6, lane = threadIdx.x & 63;
  int row = blockIdx.x * 4 + w;
  float inv = 1.0f / sume[row];
  const float2 p2 = ((const float2*)(acc + (size_t)row * Z_N))[lane];
  const float2 n2 = ((const float2*)(nxt + (size_t)row * Z_N))[lane];
  float dx = p2.x * inv - n2.x, dy = p2.y * inv - n2.y;
  float s = dx * dx + dy * dy;
#pragma unroll
  for (int m = 1; m < 64; m <<= 1) s += __shfl_xor(s, m);
  if (lane == 0) ls[w] = s;
  __syncthreads();
  if (threadIdx.x == 0) atomicAdd(loss, ls[0] + ls[1] + ls[2] + ls[3]);
}

__global__ void k_final(const float* __restrict__ loss, float* __restrict__ out) {
  out[0] = loss[0] * (1.0f / (float)(B_N * Z_N));
}

// ------------------------------------------------------------------
// ws layout (bytes):
//  acc     @ 0          1,048,576   (zeroed)
//  sume    @ 1,048,576      8,192   (zeroed)
//  loss    @ 1,056,768         16   (zeroed)
//  counts  @ 1,056,784         16
//  lists   @ 1,056,800     32,768
//  work    @ 1,089,568      4,096
//  qnb     @ 1,093,664    524,288
//  kn bf16 @ 1,617,952 51,200,000
//  vt bf16 @ 52,817,952 51,200,000  -> total ~104.0 MB
// ------------------------------------------------------------------
extern "C" void kernel_launch(void* const* d_in, const int* in_sizes, int n_in,
                              void* d_out, int out_size, void* d_ws, size_t ws_size,
                              hipStream_t stream) {
  const float* x    = (const float*)d_in[0];
  const float* nxt  = (const float*)d_in[1];
  const float* keys = (const float*)d_in[2];
  const float* vals = (const float*)d_in[3];
  const int*   act  = (const int*)d_in[4];

  char* ws = (char*)d_ws;
  float* acc    = (float*)(ws + 0);
  float* sume   = (float*)(ws + 1048576);
  float* loss   = (float*)(ws + 1056768);
  int*   counts = (int*)(ws + 1056784);
  int*   lists  = (int*)(ws + 1056800);
  int*   work   = (int*)(ws + 1089568);
  unsigned short* qnb = (unsigned short*)(ws + 1093664);
  unsigned short* kn  = (unsigned short*)(ws + 1617952);
  unsigned short* vt  = (unsigned short*)(ws + 52817952);

  hipMemsetAsync(ws, 0, 1056784, stream);

  k_norm<<<50512, 256, 0, stream>>>(keys, x, kn, qnb);
  k_vtrans<<<dim3(782, 2, A_N), 256, 0, stream>>>(vals, vt);
  k_route<<<1, 1024, 0, stream>>>(act, counts, lists, work);
  k_flash<<<640, 512, 0, stream>>>(kn, vt, qnb, counts, lists, work, acc, sume);
  k_loss<<<512, 256, 0, stream>>>(acc, sume, nxt, loss);
  k_final<<<1, 1, 0, stream>>>(loss, (float*)d_out);
}